// Round 10
// baseline (130.405 us; speedup 1.0000x reference)
//
#include <hip/hip_runtime.h>

typedef __bf16 bf16_t;
typedef __attribute__((ext_vector_type(8))) __bf16 bf16x8;
typedef __attribute__((ext_vector_type(4))) __bf16 bf16x4;
typedef __attribute__((ext_vector_type(2))) __bf16 bf16x2;
typedef __attribute__((ext_vector_type(4))) float f32x4;

#define S_LEN 4096
#define D_MODEL 1024
#define NH 16
#define DKH 64
#define WIN 256
#define NGLOB 16
#define HSZ (S_LEN * DKH)

// async 16B global->LDS copy (dest: wave-uniform base + lane*16)
__device__ inline void g2l16(const void* g, void* l) {
  __builtin_amdgcn_global_load_lds(
      (__attribute__((address_space(1))) void*)(void*)g,
      (__attribute__((address_space(3))) void*)l, 16, 0, 0);
}

// ---------------------------------------------------------------------------
// GEMM body, R6-verified sync structure (stage -> barrier -> compute ->
// barrier), 128x128 tile, BK=32, 4 waves (2x2), 4x4 frags of 16x16x32.
// AF32=true: A is raw f32; staged via g2l16 into a 16KB f32 LDS tile
//   (swizzled 16B slots: LDS[r][t] = G[r][t ^ (r&7)], t = 4-f32 slot),
//   fragments cvt'd f32->bf16 in-register at read time (fuses the convx
//   kernel; sync structure untouched).
// AF32=false: A bf16, staged exactly as R6 (verified 0 bank conflicts).
// B: bf16, R6 source-swizzled g2l16 (rule 21: dest linear).
// No sched_barrier (m141), no dynamic LDS indexing (rule 20).
// ---------------------------------------------------------------------------
template <bool AF32>
__device__ __forceinline__ void gemm_body(const void* __restrict__ Ap,
                                          const bf16_t* __restrict__ Bt,
                                          int m0, int n0, int wave, int lane,
                                          char* AsRaw, bf16_t* Bs,
                                          f32x4 acc[4][4]) {
  float* Asf = (float*)AsRaw;
  bf16_t* Ash = (bf16_t*)AsRaw;
  const float* Af = (const float*)Ap;
  const bf16_t* Ah = (const bf16_t*)Ap;
  const int wr = wave >> 1, wc = wave & 1;
#pragma unroll
  for (int i = 0; i < 4; i++)
#pragma unroll
    for (int j = 0; j < 4; j++) acc[i][j] = {0.f, 0.f, 0.f, 0.f};

  // bf16 staging consts (R6): chunk = 16 rows x 32 bf16 (1KB);
  // src slot s=(l&7)^(l>>3); row=2*(l>>3)+(s>>2); col=8*(s&3).
  const int ssl = (lane & 7) ^ (lane >> 3);
  const int srowB = 2 * (lane >> 3) + (ssl >> 2);
  const int scolB = 8 * (ssl & 3);
  // f32-A staging consts: chunk = 8 rows x 32 f32 (1KB); lane l -> dest
  // byte 16l: row=l>>3, dest slot=l&7, src slot=(l&7)^(l>>3).
  const int arowF = lane >> 3;
  const int aslotF = (lane & 7) ^ arowF;
  // fragment reads
  const int fr = lane & 15;
  const int fkg = lane >> 4;  // 16B k-slot pair index

  for (int k0 = 0; k0 < D_MODEL; k0 += 32) {
    if constexpr (AF32) {
#pragma unroll
      for (int i = 0; i < 4; i++) {  // 16 chunks of 8 rows; 4 per wave
        const int c = wave * 4 + i;
        g2l16(Af + (size_t)(m0 + c * 8 + arowF) * D_MODEL + k0 + aslotF * 4,
              &Asf[c * 256]);
      }
    } else {
#pragma unroll
      for (int i = 0; i < 2; i++) {  // 8 chunks of 16 rows; 2 per wave
        const int c = wave * 2 + i;
        g2l16(Ah + (size_t)(m0 + c * 16 + srowB) * D_MODEL + k0 + scolB,
              &Ash[c * 512]);
      }
    }
#pragma unroll
    for (int i = 0; i < 2; i++) {
      const int c = wave * 2 + i;
      g2l16(Bt + (size_t)(n0 + c * 16 + srowB) * D_MODEL + k0 + scolB,
            &Bs[c * 512]);
    }
    __syncthreads();
    bf16x8 af[4], bfr[4];
#pragma unroll
    for (int m = 0; m < 4; m++) {
      const int rr = wr * 64 + m * 16 + fr;
      if constexpr (AF32) {
        const float4 x =
            *(const float4*)&Asf[rr * 32 + (((fkg << 1) ^ (rr & 7)) << 2)];
        const float4 y =
            *(const float4*)&Asf[rr * 32 +
                                 ((((fkg << 1) | 1) ^ (rr & 7)) << 2)];
        af[m] = bf16x8{(bf16_t)x.x, (bf16_t)x.y, (bf16_t)x.z, (bf16_t)x.w,
                       (bf16_t)y.x, (bf16_t)y.y, (bf16_t)y.z, (bf16_t)y.w};
      } else {
        af[m] = *(const bf16x8*)&Ash[(rr >> 1) * 64 +
                                     ((((rr & 1) << 2) + fkg) ^
                                      ((rr >> 1) & 7)) *
                                         8];
      }
    }
#pragma unroll
    for (int n = 0; n < 4; n++) {
      const int rr = wc * 64 + n * 16 + fr;
      bfr[n] = *(const bf16x8*)&Bs[(rr >> 1) * 64 +
                                   ((((rr & 1) << 2) + fkg) ^ ((rr >> 1) & 7)) *
                                       8];
    }
#pragma unroll
    for (int m = 0; m < 4; m++)
#pragma unroll
      for (int n = 0; n < 4; n++)
        acc[m][n] = __builtin_amdgcn_mfma_f32_16x16x32_bf16(af[m], bfr[n],
                                                            acc[m][n], 0, 0, 0);
    __syncthreads();
  }
}

// ---------------------------------------------------------------------------
// Fused Q/K/V projection reading RAW f32 inputs. 768 blocks, XCD-chunked
// (96/XCD, n-fastest) so the 8 n-blocks sharing an A-panel share an L2.
// which=0: Q bf16 [h][s][64] scaled 0.125; 1: K bf16; 2: V^T bf16 [h][64][s].
// ---------------------------------------------------------------------------
__global__ __launch_bounds__(256) void gemm_qkv(
    const float* __restrict__ Xq, const float* __restrict__ Xk,
    const float* __restrict__ Xv, const bf16_t* __restrict__ Wt,
    const float* __restrict__ bq, const float* __restrict__ bk,
    const float* __restrict__ bv, bf16_t* __restrict__ Qo,
    bf16_t* __restrict__ Ko, bf16_t* __restrict__ Vto) {
  __shared__ float Asf[128 * 32];   // 16KB
  __shared__ bf16_t Bs[128 * 32];   // 8KB
  const int lin = blockIdx.x;
  const int wg = ((lin & 7) * 96) + (lin >> 3);  // 768 = 8 XCD * 96
  const int n0 = (wg & 7) * 128;
  const int m0 = ((wg >> 3) & 31) * 128;
  const int which = wg >> 8;

  const float* A = which == 0 ? Xq : which == 1 ? Xk : Xv;
  const bf16_t* Bt = Wt + (size_t)which * (D_MODEL * D_MODEL);
  const float* bias = which == 0 ? bq : which == 1 ? bk : bv;

  const int wave = threadIdx.x >> 6, lane = threadIdx.x & 63;
  f32x4 acc[4][4];
  gemm_body<true>(A, Bt, m0, n0, wave, lane, (char*)Asf, Bs, acc);

  const int wr = wave >> 1, wc = wave & 1;
  const int cr = (lane >> 4) * 4;
  const int cc = lane & 15;
#pragma unroll
  for (int m = 0; m < 4; m++) {
    const int rowg = m0 + wr * 64 + m * 16 + cr;
#pragma unroll
    for (int n = 0; n < 4; n++) {
      const int colg = n0 + wc * 64 + n * 16 + cc;
      const float bv_ = bias[colg];
      const int h = colg >> 6, d = colg & 63;
#pragma unroll
      for (int r = 0; r < 4; r++) {
        const int s = rowg + r;
        const float v = acc[m][n][r] + bv_;
        if (which == 0)
          Qo[h * HSZ + s * DKH + d] = (bf16_t)(v * 0.125f);
        else if (which == 1)
          Ko[h * HSZ + s * DKH + d] = (bf16_t)v;
        else
          Vto[h * HSZ + d * S_LEN + s] = (bf16_t)v;
      }
    }
  }
}

// Final output projection: f32 out with bias. 256 blocks, XCD-chunked.
__global__ __launch_bounds__(256) void gemm_out(const bf16_t* __restrict__ A_,
                                                const bf16_t* __restrict__ Bt_,
                                                const float* __restrict__ bias,
                                                float* __restrict__ Cout) {
  __shared__ bf16_t Ash[128 * 32];  // 8KB
  __shared__ bf16_t Bs[128 * 32];   // 8KB
  const int lin = blockIdx.x;
  const int wg = ((lin & 7) * 32) + (lin >> 3);  // 256 = 8 XCD * 32
  const int n0 = (wg & 7) * 128;
  const int m0 = (wg >> 3) * 128;
  const int wave = threadIdx.x >> 6, lane = threadIdx.x & 63;
  f32x4 acc[4][4];
  gemm_body<false>(A_, Bt_, m0, n0, wave, lane, (char*)Ash, Bs, acc);

  const int wr = wave >> 1, wc = wave & 1;
  const int cr = (lane >> 4) * 4;
  const int cc = lane & 15;
#pragma unroll
  for (int m = 0; m < 4; m++) {
    const int rowg = m0 + wr * 64 + m * 16 + cr;
#pragma unroll
    for (int n = 0; n < 4; n++) {
      const int colg = n0 + wc * 64 + n * 16 + cc;
      const float bv_ = bias[colg];
#pragma unroll
      for (int r = 0; r < 4; r++)
        Cout[(size_t)(rowg + r) * D_MODEL + colg] = acc[m][n][r] + bv_;
    }
  }
}

// transpose+convert 4 weight matrices [K,N] f32 -> [N,K] bf16
__global__ void convw(const float* __restrict__ W0, const float* __restrict__ W1,
                      const float* __restrict__ W2, const float* __restrict__ W3,
                      bf16_t* __restrict__ out) {
  __shared__ float t[64][65];
  const float* W = blockIdx.z == 0 ? W0 : blockIdx.z == 1 ? W1
                  : blockIdx.z == 2 ? W2 : W3;
  bf16_t* Wt = out + (size_t)blockIdx.z * (D_MODEL * D_MODEL);
  const int k0 = blockIdx.y * 64, n0 = blockIdx.x * 64;
  const int tx = threadIdx.x & 63, ty = threadIdx.x >> 6;
#pragma unroll
  for (int i = 0; i < 16; i++) {
    const int r = i * 4 + ty;
    t[r][tx] = W[(size_t)(k0 + r) * D_MODEL + n0 + tx];
  }
  __syncthreads();
#pragma unroll
  for (int i = 0; i < 16; i++) {
    const int r = i * 4 + ty;
    Wt[(size_t)(n0 + r) * D_MODEL + k0 + tx] = (bf16_t)t[tx][r];
  }
}

// ---------------------------------------------------------------------------
// Sparse flash attention, swapped-QK^T form (unchanged from R4 pass).
// ---------------------------------------------------------------------------
__global__ __launch_bounds__(256) void attn_kern(const bf16_t* __restrict__ Q,
                                                 const bf16_t* __restrict__ K,
                                                 const bf16_t* __restrict__ V,
                                                 bf16_t* __restrict__ O) {
  __shared__ bf16_t p_lds[4][16 * 40];  // [wave][q*40 + k], padded
  const int wave = threadIdx.x >> 6, lane = threadIdx.x & 63;
  const int h = blockIdx.y;
  const int q0 = blockIdx.x * 64 + wave * 16;
  const bf16_t* Qh = Q + h * HSZ;
  const bf16_t* Kh = K + h * HSZ;
  const bf16_t* Vh = V + h * HSZ;  // V^T: [64][S]

  const int fr = lane & 15;
  const int fk = (lane >> 4) * 8;
  const int cr = (lane >> 4) * 4;

  const bf16x8 aq0 = *(const bf16x8*)&Qh[(q0 + fr) * DKH + fk];
  const bf16x8 aq1 = *(const bf16x8*)&Qh[(q0 + fr) * DKH + 32 + fk];

  f32x4 acc_o[4];
#pragma unroll
  for (int i = 0; i < 4; i++) acc_o[i] = {0.f, 0.f, 0.f, 0.f};
  float m_run = -1e30f, l_run = 0.f;

  const int kt_end = (q0 + 15) >> 5;
  int kt_lo = (q0 - WIN) >> 5;
  if (kt_lo < 0) kt_lo = 0;
  const int nt = kt_end - kt_lo + 1 + (kt_lo > 0 ? 1 : 0);

#define TILE_KB(t) ((kt_lo > 0) ? ((t) == 0 ? 0 : (kt_lo + (t)-1) * 32) : (t)*32)
#define LOADK(kb, A0, A1, A2, A3)                              \
  A0 = *(const bf16x8*)&Kh[((kb) + fr) * DKH + fk];            \
  A1 = *(const bf16x8*)&Kh[((kb) + fr) * DKH + 32 + fk];       \
  A2 = *(const bf16x8*)&Kh[((kb) + 16 + fr) * DKH + fk];       \
  A3 = *(const bf16x8*)&Kh[((kb) + 16 + fr) * DKH + 32 + fk];

  bf16x8 kc0, kc1, kc2, kc3;
  {
    const int kb0 = TILE_KB(0);
    LOADK(kb0, kc0, kc1, kc2, kc3)
  }

  const int iq = q0 + fr;
  bf16_t* prow = &p_lds[wave][fr * 40];
  const bf16x8* pread = (const bf16x8*)&p_lds[wave][fr * 40 + fk];

  for (int t = 0; t < nt; t++) {
    const int kb = TILE_KB(t);
    bf16x8 kn0, kn1, kn2, kn3;
    const bool have_next = (t + 1 < nt);
    if (have_next) {
      const int nkb = TILE_KB(t + 1);
      LOADK(nkb, kn0, kn1, kn2, kn3)
    }
    bf16x8 vf0 = *(const bf16x8*)&Vh[(0 * 16 + fr) * S_LEN + kb + fk];
    bf16x8 vf1 = *(const bf16x8*)&Vh[(1 * 16 + fr) * S_LEN + kb + fk];
    bf16x8 vf2 = *(const bf16x8*)&Vh[(2 * 16 + fr) * S_LEN + kb + fk];
    bf16x8 vf3 = *(const bf16x8*)&Vh[(3 * 16 + fr) * S_LEN + kb + fk];

    f32x4 s0 = {0.f, 0.f, 0.f, 0.f}, s1 = {0.f, 0.f, 0.f, 0.f};
    s0 = __builtin_amdgcn_mfma_f32_16x16x32_bf16(kc0, aq0, s0, 0, 0, 0);
    s0 = __builtin_amdgcn_mfma_f32_16x16x32_bf16(kc1, aq1, s0, 0, 0, 0);
    s1 = __builtin_amdgcn_mfma_f32_16x16x32_bf16(kc2, aq0, s1, 0, 0, 0);
    s1 = __builtin_amdgcn_mfma_f32_16x16x32_bf16(kc3, aq1, s1, 0, 0, 0);

    float v[8];
#pragma unroll
    for (int r = 0; r < 4; r++) {
      const int j0 = kb + cr + r, j1 = j0 + 16;
      v[r] = (j0 <= iq && (iq - j0 <= WIN || j0 < NGLOB)) ? s0[r] : -1e30f;
      v[4 + r] = (j1 <= iq && (iq - j1 <= WIN || j1 < NGLOB)) ? s1[r] : -1e30f;
    }
    float mt = fmaxf(fmaxf(fmaxf(v[0], v[1]), fmaxf(v[2], v[3])),
                     fmaxf(fmaxf(v[4], v[5]), fmaxf(v[6], v[7])));
    mt = fmaxf(mt, __shfl_xor(mt, 16));
    mt = fmaxf(mt, __shfl_xor(mt, 32));
    const float mn = fmaxf(m_run, mt);
    const float alpha = __expf(m_run - mn);
    m_run = mn;
    float p[8];
    float ps = 0.f;
#pragma unroll
    for (int i = 0; i < 8; i++) {
      p[i] = __expf(v[i] - mn);
      ps += p[i];
    }
    ps += __shfl_xor(ps, 16);
    ps += __shfl_xor(ps, 32);
    l_run = l_run * alpha + ps;

    *(bf16x2*)&prow[cr] = bf16x2{(bf16_t)p[0], (bf16_t)p[1]};
    *(bf16x2*)&prow[cr + 2] = bf16x2{(bf16_t)p[2], (bf16_t)p[3]};
    *(bf16x2*)&prow[16 + cr] = bf16x2{(bf16_t)p[4], (bf16_t)p[5]};
    *(bf16x2*)&prow[16 + cr + 2] = bf16x2{(bf16_t)p[6], (bf16_t)p[7]};

    float alpha_r[4];
#pragma unroll
    for (int r = 0; r < 4; r++) alpha_r[r] = __shfl(alpha, cr + r);

    asm volatile("" ::: "memory");
    const bf16x8 pa = *pread;
    asm volatile("" ::: "memory");

#pragma unroll
    for (int fd = 0; fd < 4; fd++) {
#pragma unroll
      for (int r = 0; r < 4; r++) acc_o[fd][r] *= alpha_r[r];
    }
    acc_o[0] = __builtin_amdgcn_mfma_f32_16x16x32_bf16(pa, vf0, acc_o[0], 0, 0, 0);
    acc_o[1] = __builtin_amdgcn_mfma_f32_16x16x32_bf16(pa, vf1, acc_o[1], 0, 0, 0);
    acc_o[2] = __builtin_amdgcn_mfma_f32_16x16x32_bf16(pa, vf2, acc_o[2], 0, 0, 0);
    acc_o[3] = __builtin_amdgcn_mfma_f32_16x16x32_bf16(pa, vf3, acc_o[3], 0, 0, 0);

    if (have_next) {
      kc0 = kn0; kc1 = kn1; kc2 = kn2; kc3 = kn3;
    }
  }

  const float linv = 1.0f / l_run;
  float inv_r[4];
#pragma unroll
  for (int r = 0; r < 4; r++) inv_r[r] = __shfl(linv, cr + r);

#pragma unroll
  for (int fd = 0; fd < 4; fd++)
#pragma unroll
    for (int r = 0; r < 4; r++) {
      const int s = q0 + cr + r;
      O[(size_t)s * D_MODEL + h * DKH + fd * 16 + fr] =
          (bf16_t)(acc_o[fd][r] * inv_r[r]);
    }
}

extern "C" void kernel_launch(void* const* d_in, const int* in_sizes, int n_in,
                              void* d_out, int out_size, void* d_ws,
                              size_t ws_size, hipStream_t stream) {
  const float* query = (const float*)d_in[0];
  const float* key = (const float*)d_in[1];
  const float* value = (const float*)d_in[2];
  const float* Wq = (const float*)d_in[3];
  const float* bq = (const float*)d_in[4];
  const float* Wk = (const float*)d_in[5];
  const float* bk = (const float*)d_in[6];
  const float* Wv = (const float*)d_in[7];
  const float* bv = (const float*)d_in[8];
  const float* Wo = (const float*)d_in[9];
  const float* bo = (const float*)d_in[10];

  char* ws = (char*)d_ws;
  bf16_t* Qb = (bf16_t*)(ws);                   // 8 MiB [16][4096][64]
  bf16_t* Kb = (bf16_t*)(ws + (8ull << 20));    // 8 MiB
  bf16_t* Vtb = (bf16_t*)(ws + (16ull << 20));  // 8 MiB [16][64][4096]
  bf16_t* Wt = (bf16_t*)(ws + (24ull << 20));   // 4 x 2 MiB (Wq^T..Wo^T)
  bf16_t* Ab = (bf16_t*)(ws + (32ull << 20));   // 8 MiB attn out [4096][1024]

  const size_t WSTRIDE = (size_t)D_MODEL * D_MODEL;

  convw<<<dim3(16, 16, 4), 256, 0, stream>>>(Wq, Wk, Wv, Wo, Wt);

  gemm_qkv<<<768, 256, 0, stream>>>(query, key, value, Wt, bq, bk, bv, Qb, Kb,
                                    Vtb);

  attn_kern<<<dim3(64, 16), 256, 0, stream>>>(Qb, Kb, Vtb, Ab);

  gemm_out<<<256, 256, 0, stream>>>(Ab, Wt + 3 * WSTRIDE, bo, (float*)d_out);
}